// Round 7
// baseline (124.026 us; speedup 1.0000x reference)
//
#include <hip/hip_runtime.h>

namespace {

constexpr int B = 4;
constexpr int M = 128;
constexpr int ITP = 10;
constexpr int P = M * ITP;            // 1280 queries per batch
constexpr int NPTS = 20000;
constexpr int NQ = B * P;             // 5120 queries
constexpr int QPW = 8;                // queries per wave
constexpr int WPB = 4;                // waves per block -> 32 queries/block
constexpr int QPB = QPW * WPB;        // 32
constexpr int NCHUNKS = 8;
constexpr int CHUNK = NPTS / NCHUNKS; // 2500
constexpr int GX = NQ / QPB;          // 160 query-group blocks in x
constexpr int FULL_ITERS = CHUNK / 64;            // 39
constexpr int TAIL = CHUNK - FULL_ITERS * 64;     // 4
constexpr int C4 = CHUNK * 3 / 4;     // 1875 float4 per chunk (30000 B, 16B-divisible)
constexpr float EPSF = 0.01f;

// t = linspace(0,1,10): nearest-f32 of j/9
__device__ const float T_TAB[ITP] = {0.0f,
    (float)(1.0 / 9.0), (float)(2.0 / 9.0), (float)(3.0 / 9.0),
    (float)(4.0 / 9.0), (float)(5.0 / 9.0), (float)(6.0 / 9.0),
    (float)(7.0 / 9.0), (float)(8.0 / 9.0), 1.0f};

// Interpolated cage point, replicating reference rounding (mul,mul,add; no fma)
__device__ __forceinline__ void query_point(const float* __restrict__ cage,
                                            int b, int p,
                                            float& x, float& y, float& z) {
  const int m = p / ITP;
  const int j = p - m * ITP;
  const float t = T_TAB[j];
  const float omt = __fsub_rn(1.0f, t);
  const float* c0 = cage + ((size_t)b * M + m) * 3;
  const float* c1 = cage + ((size_t)b * M + ((m + 1) & (M - 1))) * 3;
  x = __fadd_rn(__fmul_rn(t, c1[0]), __fmul_rn(omt, c0[0]));
  y = __fadd_rn(__fmul_rn(t, c1[1]), __fmul_rn(omt, c0[1]));
  z = __fadd_rn(__fmul_rn(t, c1[2]), __fmul_rn(omt, c0[2]));
}

// One point vs QPW queries: exact reference formula d2 = (cc+ss) - 2*dot.
__device__ __forceinline__ void updateQ(const float px, const float py,
                                        const float pz, const float ss,
                                        const int n,
                                        const float* __restrict__ cx,
                                        const float* __restrict__ cy,
                                        const float* __restrict__ cz,
                                        const float* __restrict__ cc,
                                        float* __restrict__ minv,
                                        unsigned int* __restrict__ mini) {
#pragma unroll
  for (int i = 0; i < QPW; ++i) {
    const float dot = __fmaf_rn(cz[i], pz, __fmaf_rn(cy[i], py, __fmul_rn(cx[i], px)));
    const float d2 = __fmaf_rn(-2.0f, dot, __fadd_rn(cc[i], ss));
    if (d2 < minv[i]) { minv[i] = d2; mini[i] = (unsigned int)n; }  // strict <: first idx wins
  }
}

// Fully fused kernel: grid (GX=160, NCHUNKS=8), 256 threads.
// Phase 1 (all blocks): LDS-stage chunk, argmin scan, write packed partials.
// Phase 2 (last block per group, ticketed): merge 8 chunk partials per query
//   in chunk-index order, compute loss for the group's 32 queries, fixed-order
//   tree reduce -> gsum[bx].
// Phase 3 (last group overall, ticketed): sum gsum[0..159] fixed-order -> mean.
__global__ __launch_bounds__(256) void k_fused(
    const float* __restrict__ cage,
    const float* __restrict__ shape,
    const float* __restrict__ normals,
    unsigned long long* __restrict__ part,
    unsigned int* __restrict__ ticket_x,   // [GX]
    unsigned int* __restrict__ tick2,      // [1]
    float* __restrict__ gsum,              // [GX]
    float* __restrict__ out) {
  __shared__ float4 smem4[C4];             // 30000 B chunk stage
  __shared__ float red[256];
  __shared__ unsigned int flag;

  const int tid  = threadIdx.x;
  const int lane = tid & 63;
  const int wid  = tid >> 6;
  const int bx   = blockIdx.x;             // query group block (32 queries)
  const int ck   = blockIdx.y;             // chunk
  const int q0   = bx * QPB + wid * QPW;
  const int b    = (bx * QPB) / P;         // uniform per block (32 | 1280)
  const int p0   = q0 - b * P;

  // ---- stage chunk into LDS (float4 x 1875; all offsets 16B-aligned) ----
  const float4* g4 = reinterpret_cast<const float4*>(shape + (size_t)b * NPTS * 3)
                     + (size_t)ck * C4;
  for (int i = tid; i < C4; i += 256) smem4[i] = g4[i];

  // ---- per-wave query setup (overlaps staging latency) ----
  float cx[QPW], cy[QPW], cz[QPW], cc[QPW];
#pragma unroll
  for (int i = 0; i < QPW; ++i) {
    float x, y, z;
    query_point(cage, b, p0 + i, x, y, z);
    cx[i] = x; cy[i] = y; cz[i] = z;
    cc[i] = __fadd_rn(__fadd_rn(__fmul_rn(x, x), __fmul_rn(y, y)), __fmul_rn(z, z));
  }
  float minv[QPW];
  unsigned int mini[QPW];
#pragma unroll
  for (int i = 0; i < QPW; ++i) { minv[i] = __int_as_float(0x7f800000); mini[i] = 0u; }

  __syncthreads();
  const float* sm = reinterpret_cast<const float*>(smem4);
  const int nbase = ck * CHUNK;

  // ---- scan loop: pure VALU + LDS, no global traffic ----
#pragma unroll 4
  for (int it = 0; it < FULL_ITERS; ++it) {
    const int j = it * 64 + lane;
    const float px = sm[3 * j], py = sm[3 * j + 1], pz = sm[3 * j + 2];
    const float ss = __fadd_rn(__fadd_rn(__fmul_rn(px, px), __fmul_rn(py, py)),
                               __fmul_rn(pz, pz));
    updateQ(px, py, pz, ss, nbase + j, cx, cy, cz, cc, minv, mini);
  }
  {  // tail: 4 valid lanes; others read lane index 0..59 (in-bounds) and mask via +inf
    const int j = (lane < TAIL) ? (FULL_ITERS * 64 + lane) : lane;
    const float px = sm[3 * j], py = sm[3 * j + 1], pz = sm[3 * j + 2];
    float ss = __fadd_rn(__fadd_rn(__fmul_rn(px, px), __fmul_rn(py, py)),
                         __fmul_rn(pz, pz));
    if (lane >= TAIL) ss = __int_as_float(0x7f800000);
    updateQ(px, py, pz, ss, nbase + j, cx, cy, cz, cc, minv, mini);
  }

  // ---- per-wave argmin reduce, write packed partials ----
#pragma unroll
  for (int i = 0; i < QPW; ++i) {
    unsigned int fb = __float_as_uint(minv[i]);
    fb = (fb & 0x80000000u) ? ~fb : (fb | 0x80000000u);  // monotone total order
    unsigned long long pk = ((unsigned long long)fb << 32) | (unsigned long long)mini[i];
#pragma unroll
    for (int s = 32; s >= 1; s >>= 1) {
      const unsigned long long o = __shfl_xor(pk, s, 64);
      pk = (o < pk) ? o : pk;   // equal d2 -> smaller idx (first-index tie-break)
    }
    if (lane == i) part[(size_t)(q0 + i) * NCHUNKS + ck] = pk;
  }

  // ---- group ticket: last of the 8 chunk-blocks for this bx does the merge ----
  __syncthreads();                 // all waves' stores issued (barrier drains vmcnt)
  __threadfence();                 // release: partials visible device-wide
  if (tid == 0) {
    const unsigned int o = atomicAdd(&ticket_x[bx], 1u);
    flag = ((o & 7u) == 7u) ? 1u : 0u;   // works for any initial value (poison-safe)
    if (flag) atomicExch(&ticket_x[bx], 0u);  // reset for next replay
  }
  __syncthreads();
  if (!flag) return;
  __threadfence();                 // acquire: see other blocks' partials

  // ---- phase 2: merge + loss for this group's 32 queries ----
  const int ql = tid >> 3;         // 0..31 query-local
  const int c  = tid & 7;          // 0..7 chunk
  unsigned long long v = part[(size_t)(bx * QPB + ql) * NCHUNKS + c];
#pragma unroll
  for (int s = 1; s < 8; s <<= 1) {   // min over the 8-lane subgroup (within wave)
    const unsigned long long o = __shfl_xor(v, s, 64);
    v = (o < v) ? o : v;
  }
  float lossv = 0.0f;
  if (c == 0) {
    const int idx = (int)(v & 0xffffffffu);
    const int q = bx * QPB + ql;
    const int p = q - b * P;
    float qx, qy, qz;
    query_point(cage, b, p, qx, qy, qz);
    const float* sp = shape   + ((size_t)b * NPTS + idx) * 3;
    const float* sn = normals + ((size_t)b * NPTS + idx) * 3;
    const float nx = sn[0], ny = sn[1], nz = sn[2];
    const float vx = __fsub_rn(__fsub_rn(qx, sp[0]), __fmul_rn(EPSF, nx));
    const float vy = __fsub_rn(__fsub_rn(qy, sp[1]), __fmul_rn(EPSF, ny));
    const float vz = __fsub_rn(__fsub_rn(qz, sp[2]), __fmul_rn(EPSF, nz));
    const float dot = __fadd_rn(__fadd_rn(__fmul_rn(vx, nx), __fmul_rn(vy, ny)),
                                __fmul_rn(vz, nz));
    lossv = (dot < 0.0f) ? -dot : 0.0f;
    red[ql] = lossv;               // red[0..31]
  }
  __syncthreads();
#pragma unroll
  for (int s = 16; s >= 1; s >>= 1) {  // fixed-order tree over 32
    if (tid < s) red[tid] = __fadd_rn(red[tid], red[tid + s]);
    __syncthreads();
  }
  if (tid == 0) gsum[bx] = red[0];

  // ---- global ticket: last group block sums all group sums ----
  __threadfence();                 // release gsum
  if (tid == 0) {
    const unsigned int o = atomicAdd(tick2, 1u);
    flag = ((o % (unsigned)GX) == (unsigned)(GX - 1)) ? 1u : 0u;
    if (flag) atomicExch(tick2, 0u);   // reset -> wrap-proof for all later replays
  }
  __syncthreads();
  if (!flag) return;
  __threadfence();                 // acquire gsum

  red[tid] = (tid < GX) ? gsum[tid] : 0.0f;
  __syncthreads();
#pragma unroll
  for (int s = 128; s >= 1; s >>= 1) {
    if (tid < s) red[tid] = __fadd_rn(red[tid], red[tid + s]);
    __syncthreads();
  }
  if (tid == 0) out[0] = red[0] / (float)NQ;
}

}  // namespace

extern "C" void kernel_launch(void* const* d_in, const int* in_sizes, int n_in,
                              void* d_out, int out_size, void* d_ws, size_t ws_size,
                              hipStream_t stream) {
  (void)in_sizes; (void)n_in; (void)out_size; (void)ws_size;
  const float* cage    = (const float*)d_in[0];
  const float* shape   = (const float*)d_in[1];
  const float* normals = (const float*)d_in[2];
  float* out = (float*)d_out;

  char* ws = (char*)d_ws;
  unsigned long long* part = (unsigned long long*)ws;            // 5120*8*8B = 320 KB
  unsigned int* ticket_x   = (unsigned int*)(ws + 320 * 1024);   // 160 u32
  unsigned int* tick2      = (unsigned int*)(ws + 321 * 1024);   // 1 u32
  float* gsum              = (float*)(ws + 322 * 1024);          // 160 f32

  dim3 grid(GX, NCHUNKS);   // 160 x 8 = 1280 blocks (5/CU balanced), 4 waves each
  k_fused<<<grid, 256, 0, stream>>>(cage, shape, normals, part, ticket_x, tick2,
                                    gsum, out);
}